// Round 7
// baseline (183.963 us; speedup 1.0000x reference)
//
#include <hip/hip_runtime.h>
#include <hip/hip_bf16.h>
#include <stdint.h>

// out = softmax(relu(X @ new_weight)), new_weight = weight + MLP(feat)[...,0].
// hidden features collapse analytically to bit features of (n,m); layer-1 is
// rank-1 + separable -> per-row table rn[n][10] + per-col table cm[m][10],
// computed inline per k_nw block.
// GEMM: fp16 2-term W-split:  logit = fp16(x) * (wh + wl),
//   wh = fp16(w), wl = fp16(w - wh)  ->  W exact to ~2^-22, only X truncated
//   at fp16 (2^-11 rel). MFMA 16x16x32_f16, tile 128x64, BK=64, LDS 32 KB.
// R7: split-K=2 -> grid 1024 = 4 blocks/CU (was 512 = 2/CU): doubles
//   co-resident blocks so one block's MFMA hides another's barrier/vmcnt
//   drain [m114]. Halves write raw f32 partials to C0/C1; softmax fuses
//   relu(c0+c1). XCD swizzle kept (per-XCD: A 1 MB + B 4 MB L2-resident).
//
// 4 dispatches: k_pre (sums) -> k_nw (MLP + X cast) -> k_gemm7 -> k_softmax3.
//
// ws layout (bytes):
//   rs      @ 0        : f32[1024]          row sums of weight
//   cs_part @ 4096     : f32[64][1024]      per-block partial col sums
//   Bt      @ 266240   : f16[1024][2048]    new_weight^T hi|lo   (4 MB)
//   Ah      @ 4460544  : f16[4096][1024]    fp16(X)              (8 MB)
//   C0      @ 12849152 : f32[4096][1024]    K-half-0 partials   (16 MB)
//   C1      @ 29626368 : f32[4096][1024]    K-half-1 partials   (16 MB)

#define RS_OFF      0
#define CSPART_OFF  4096
#define BT_OFF      266240
#define AH_OFF      4460544
#define C0_OFF      12849152
#define C1_OFF      29626368

typedef __attribute__((ext_vector_type(8))) _Float16 f16x8;
typedef __attribute__((ext_vector_type(4))) float f32x4;

__device__ __forceinline__ unsigned short f2h(float x) {
    _Float16 h = (_Float16)x;            // RNE
    unsigned short u;
    __builtin_memcpy(&u, &h, 2);
    return u;
}
__device__ __forceinline__ float h2f(unsigned short u) {
    _Float16 h;
    __builtin_memcpy(&h, &u, 2);
    return (float)h;
}
__device__ __forceinline__ void gld16(const void* g, void* l) {
    __builtin_amdgcn_global_load_lds(
        (const __attribute__((address_space(1))) unsigned*)g,
        (__attribute__((address_space(3))) unsigned*)l, 16, 0, 0);
}

// ---------------------------------------------------------------------------
// K1: row sums (wave per 4 rows, shuffle) + 64 partial colsum vectors.
__global__ __launch_bounds__(256) void k_pre(const float* __restrict__ w,
        float* __restrict__ rs, float* __restrict__ cs_part) {
    __shared__ float part[4][1024];
    int t = threadIdx.x;
    int lane = t & 63, wv = t >> 6;
    int r0 = blockIdx.x * 16 + wv * 4;
    float ccol[16];
    #pragma unroll
    for (int j = 0; j < 16; ++j) ccol[j] = 0.f;
    #pragma unroll
    for (int rr = 0; rr < 4; ++rr) {
        int row = r0 + rr;
        float rsum = 0.f;
        #pragma unroll
        for (int j = 0; j < 16; ++j) {
            float v = w[(size_t)row * 1024 + j * 64 + lane];
            ccol[j] += v;
            rsum += v;
        }
        #pragma unroll
        for (int o = 32; o; o >>= 1) rsum += __shfl_down(rsum, o);
        if (lane == 0) rs[row] = rsum;
    }
    #pragma unroll
    for (int j = 0; j < 16; ++j) part[wv][j * 64 + lane] = ccol[j];
    __syncthreads();
    #pragma unroll
    for (int j = 0; j < 4; ++j) {
        int c = t + j * 256;
        cs_part[(size_t)blockIdx.x * 1024 + c] =
            part[0][c] + part[1][c] + part[2][c] + part[3][c];
    }
}

// ---------------------------------------------------------------------------
// K2: blocks 0..1023: new_weight MLP on 32x32 tiles (inline rn/cm tables +
// colsum reduction), writing TRANSPOSED fp16 hi/lo Bt. Blocks 1024..2047:
// cast X -> fp16 Ah (memory-bound; overlaps the compute-bound MLP blocks).
__global__ __launch_bounds__(256) void k_nw(const float* __restrict__ w,
        const float* __restrict__ X,
        const float* __restrict__ rs, const float* __restrict__ cs_part,
        const float* __restrict__ W1, const float* __restrict__ b1,
        const float* __restrict__ W2, const float* __restrict__ b2,
        const float* __restrict__ W3, const float* __restrict__ b3,
        unsigned short* __restrict__ Bt, unsigned short* __restrict__ Ah) {
    __shared__ float sW1[630], sW2[100], sb1[10], sb2[10], sw3[10], sa[10];
    __shared__ float rs_loc[32], cs_loc[32];
    __shared__ float rn_loc[320], cm_loc[320];
    __shared__ float st[32][33];   // +1 pad: conflict-free column reads
    int t = threadIdx.x;
    if (blockIdx.x >= 1024) {
        int b2x = blockIdx.x - 1024;        // 0..1023, 4096 floats each
        #pragma unroll
        for (int p = 0; p < 4; ++p) {
            size_t idx = (size_t)b2x * 4096 + p * 1024 + t * 4;
            float4 v = *(const float4*)&X[idx];
            ushort4 h;
            h.x = f2h(v.x); h.y = f2h(v.y); h.z = f2h(v.z); h.w = f2h(v.w);
            *(ushort4*)&Ah[idx] = h;
        }
        return;
    }
    int n0 = (blockIdx.x & 31) * 32;   // weight-row base (k of gemm)
    int m0 = (blockIdx.x >> 5) * 32;   // weight-col base (n of gemm)
    const float inv = 1.0f / 1023.0f;

    for (int i = t; i < 630; i += 256) sW1[i] = W1[i];
    if (t < 100) sW2[t] = W2[t];
    if (t >= 128 && t < 138) { sb1[t - 128] = b1[t - 128]; sb2[t - 128] = b2[t - 128]; }
    if (t >= 160 && t < 170) sw3[t - 160] = W3[(t - 160) * 21];  // W3[:,0]
    if (t >= 192 && t < 224) rs_loc[t - 192] = rs[n0 + t - 192];
    if (t >= 224 && t < 256) {
        float s = 0.f;
        #pragma unroll
        for (int p = 0; p < 64; ++p) s += cs_part[(size_t)p * 1024 + m0 + (t - 224)];
        cs_loc[t - 224] = s;
    }
    float b30 = b3[0];
    __syncthreads();
    if (t < 10) sa[t] = sW1[t] - (sW1[10 + t] + sW1[20 + t]) * inv;
    // rn/cm tables for this block's 32 rows / 32 cols (640 values)
    for (int id = t; id < 640; id += 256) {
        int h = id % 10, i = (id / 10) & 31, side = id >= 320;
        if (!side) {
            int n = n0 + i;
            float v = rs_loc[i] * sW1[20 + h] * inv;
            #pragma unroll
            for (int j = 0; j < 10; j++) {
                float bit = (float)((n >> (9 - j)) & 1);
                v += bit * (sW1[(3 + j) * 10 + h] + sW1[(43 + j) * 10 + h]
                            - sW1[(23 + j) * 10 + h] * inv);
                v += (512.0f * inv) * sW1[(23 + j) * 10 + h];
            }
            rn_loc[i * 10 + h] = v;
        } else {
            int m = m0 + i;
            float v = cs_loc[i] * sW1[10 + h] * inv + sb1[h];
            #pragma unroll
            for (int j = 0; j < 10; j++) {
                float bit = (float)((m >> (9 - j)) & 1);
                v += bit * (sW1[(13 + j) * 10 + h] + sW1[(33 + j) * 10 + h]
                            - sW1[(53 + j) * 10 + h] * inv);
                v += (512.0f * inv) * sW1[(53 + j) * 10 + h];
            }
            cm_loc[i * 10 + h] = v;
        }
    }
    __syncthreads();
    int ml = t & 31;
    #pragma unroll
    for (int i = 0; i < 4; i++) {
        int nl = (t >> 5) + 8 * i;
        float wv = w[(size_t)(n0 + nl) * 1024 + m0 + ml];
        float h1[10];
        #pragma unroll
        for (int h = 0; h < 10; h++)
            h1[h] = fmaxf(wv * sa[h] + rn_loc[nl * 10 + h] + cm_loc[ml * 10 + h], 0.f);
        float u = b30;
        #pragma unroll
        for (int k = 0; k < 10; k++) {
            float h2 = sb2[k];
            #pragma unroll
            for (int h = 0; h < 10; h++) h2 += h1[h] * sW2[h * 10 + k];
            u += fmaxf(h2, 0.f) * sw3[k];
        }
        st[nl][ml] = wv + u;
    }
    __syncthreads();
    int mrow = t >> 3, kc = t & 7;
    unsigned short hi4[4], lo4[4];
    #pragma unroll
    for (int j = 0; j < 4; j++) {
        float v = st[kc * 4 + j][mrow];
        unsigned short h = f2h(v);
        hi4[j] = h;
        lo4[j] = f2h(v - h2f(h));
    }
    size_t base = (size_t)(m0 + mrow) * 2048 + n0 + kc * 4;
    *(ushort4*)&Bt[base]        = make_ushort4(hi4[0], hi4[1], hi4[2], hi4[3]);
    *(ushort4*)&Bt[base + 1024] = make_ushort4(lo4[0], lo4[1], lo4[2], lo4[3]);
}

// ---------------------------------------------------------------------------
// K3: split-K=2 fp16 MFMA gemm. Each block: 128(M)x64(N) tile, K-half of 512
// (8 iters of BK=64), raw f32 partials to C0/C1 (relu deferred to softmax).
// Grid 1024 = 4 blocks/CU (LDS 32 KB x4 = 128 KB). XCD-aware swizzle: xcd
// owns 4 m-groups x 16 n x both halves -> per-XCD A 1 MB + B 4 MB in L2.
// XOR-swizzled LDS chunks (pos = row*8 + (seg ^ (row&7))): staging stays
// lane-contiguous for global_load_lds, frag reads spread over all bank-quads.
__global__ __launch_bounds__(256, 4) void k_gemm7(const unsigned short* __restrict__ Ah,
        const unsigned short* __restrict__ Bt,
        float* __restrict__ C0, float* __restrict__ C1) {
    __shared__ unsigned short sAh[128 * 64];                  // 16 KB
    __shared__ unsigned short sBh[64 * 64], sBl[64 * 64];     // 8 KB each
    int tid = threadIdx.x;
    int lane = tid & 63, w = tid >> 6;
    // b = (xcd, s); s = (half, slot64); slot64 = (ty_local, tx)
    int b = blockIdx.x;
    int xcd = b & 7, s = b >> 3;          // s in [0,128)
    int half = s >> 6;                    // 0,1
    int s2 = s & 63;
    int ty = (xcd << 2) | (s2 >> 4);
    int tx = s2 & 15;
    int n0 = tx * 64, m0 = ty * 128;
    int k0 = half * 512;
    float* __restrict__ C = half ? C1 : C0;
    int wm = (w >> 1) * 64, wn = (w & 1) * 32;
    int quad = lane >> 4, l16 = lane & 15;

    f32x4 acc[4][2];
    #pragma unroll
    for (int i = 0; i < 4; i++)
        #pragma unroll
        for (int j = 0; j < 2; j++) acc[i][j] = (f32x4)0.f;

    for (int it = 0; it < 8; ++it) {
        int kb = k0 + it * 64;
        __syncthreads();
        // A: 1024 chunks (128 rows x 8 segs), 4 per thread
        #pragma unroll
        for (int s3 = 0; s3 < 4; ++s3) {
            int P = s3 * 256 + tid;
            int row = P >> 3;
            int seg = (P & 7) ^ (row & 7);
            int ldsOff = (s3 * 256 + w * 64) * 8;       // wave-uniform dst
            size_t ga = (size_t)(m0 + row) * 1024 + kb + seg * 8;
            gld16(&Ah[ga], &sAh[ldsOff]);
        }
        // B: 512 chunks per buffer (64 rows x 8 segs), hi+lo
        #pragma unroll
        for (int s3 = 0; s3 < 2; ++s3) {
            int P = s3 * 256 + tid;
            int row = P >> 3;
            int seg = (P & 7) ^ (row & 7);
            int ldsOff = (s3 * 256 + w * 64) * 8;
            size_t gb = (size_t)(n0 + row) * 2048 + kb + seg * 8;
            gld16(&Bt[gb], &sBh[ldsOff]);
            gld16(&Bt[gb + 1024], &sBl[ldsOff]);
        }
        __syncthreads();
        #pragma unroll
        for (int ks = 0; ks < 2; ++ks) {
            int segk = ks * 4 + quad;
            f16x8 ah[4], bh[2], bl[2];
            #pragma unroll
            for (int i = 0; i < 4; ++i) {
                int ra = wm + i * 16 + l16;
                int ca = (ra * 8 + (segk ^ (ra & 7))) * 8;
                ah[i] = *(const f16x8*)&sAh[ca];
            }
            #pragma unroll
            for (int j = 0; j < 2; ++j) {
                int rb = wn + j * 16 + l16;
                int cb = (rb * 8 + (segk ^ (rb & 7))) * 8;
                bh[j] = *(const f16x8*)&sBh[cb];
                bl[j] = *(const f16x8*)&sBl[cb];
            }
            #pragma unroll
            for (int i = 0; i < 4; ++i)
                #pragma unroll
                for (int j = 0; j < 2; ++j) {
                    acc[i][j] = __builtin_amdgcn_mfma_f32_16x16x32_f16(ah[i], bh[j], acc[i][j], 0, 0, 0);
                    acc[i][j] = __builtin_amdgcn_mfma_f32_16x16x32_f16(ah[i], bl[j], acc[i][j], 0, 0, 0);
                }
        }
    }
    // C/D layout: col = lane&15, row = quad*4 + reg  [measured m89/m91]
    #pragma unroll
    for (int i = 0; i < 4; ++i) {
        int mr = m0 + wm + i * 16 + quad * 4;
        #pragma unroll
        for (int j = 0; j < 2; ++j) {
            int nc = n0 + wn + j * 16 + l16;
            #pragma unroll
            for (int r = 0; r < 4; ++r)
                C[(size_t)(mr + r) * 1024 + nc] = acc[i][j][r];
        }
    }
}

// ---------------------------------------------------------------------------
// K4: fused add + relu + row softmax: out = softmax(relu(C0+C1)) per row.
__global__ __launch_bounds__(256) void k_softmax3(const float* __restrict__ C0,
        const float* __restrict__ C1, float* __restrict__ out) {
    int row = blockIdx.x, t = threadIdx.x, lane = t & 63, wv = t >> 6;
    __shared__ float red[8];
    size_t base = (size_t)row * 1024 + t * 4;
    float4 a = *(const float4*)&C0[base];
    float4 bq = *(const float4*)&C1[base];
    float4 v;
    v.x = fmaxf(a.x + bq.x, 0.f);
    v.y = fmaxf(a.y + bq.y, 0.f);
    v.z = fmaxf(a.z + bq.z, 0.f);
    v.w = fmaxf(a.w + bq.w, 0.f);
    float lm = fmaxf(fmaxf(v.x, v.y), fmaxf(v.z, v.w));
    #pragma unroll
    for (int o = 32; o; o >>= 1) lm = fmaxf(lm, __shfl_down(lm, o));
    if (lane == 0) red[wv] = lm;
    __syncthreads();
    float mx = fmaxf(fmaxf(red[0], red[1]), fmaxf(red[2], red[3]));
    float4 e;
    e.x = __expf(v.x - mx); e.y = __expf(v.y - mx);
    e.z = __expf(v.z - mx); e.w = __expf(v.w - mx);
    float ls = e.x + e.y + e.z + e.w;
    #pragma unroll
    for (int o = 32; o; o >>= 1) ls += __shfl_down(ls, o);
    if (lane == 0) red[4 + wv] = ls;
    __syncthreads();
    float inv = 1.0f / (red[4] + red[5] + red[6] + red[7]);
    e.x *= inv; e.y *= inv; e.z *= inv; e.w *= inv;
    *(float4*)&out[base] = e;
}

// ---------------------------------------------------------------------------
extern "C" void kernel_launch(void* const* d_in, const int* in_sizes, int n_in,
                              void* d_out, int out_size, void* d_ws, size_t ws_size,
                              hipStream_t stream) {
    const float* X  = (const float*)d_in[0];
    const float* W  = (const float*)d_in[1];
    // d_in[2] = hidden: analytic, never read
    const float* W1 = (const float*)d_in[3];
    const float* b1 = (const float*)d_in[4];
    const float* W2 = (const float*)d_in[5];
    const float* b2 = (const float*)d_in[6];
    const float* W3 = (const float*)d_in[7];
    const float* b3 = (const float*)d_in[8];

    char* wsb = (char*)d_ws;
    float* rs            = (float*)(wsb + RS_OFF);
    float* cs_part       = (float*)(wsb + CSPART_OFF);
    unsigned short* Bt   = (unsigned short*)(wsb + BT_OFF);
    unsigned short* Ah   = (unsigned short*)(wsb + AH_OFF);
    float* C0            = (float*)(wsb + C0_OFF);
    float* C1            = (float*)(wsb + C1_OFF);
    float* out = (float*)d_out;

    k_pre<<<64, 256, 0, stream>>>(W, rs, cs_part);
    k_nw<<<2048, 256, 0, stream>>>(W, X, rs, cs_part, W1, b1, W2, b2, W3, b3, Bt, Ah);
    k_gemm7<<<1024, 256, 0, stream>>>(Ah, Bt, C0, C1);
    k_softmax3<<<4096, 256, 0, stream>>>(C0, C1, out);
}

// Round 8
// 181.554 us; speedup vs baseline: 1.0133x; 1.0133x over previous
//
#include <hip/hip_runtime.h>
#include <hip/hip_bf16.h>
#include <stdint.h>

// out = softmax(relu(X @ new_weight)), new_weight = weight + MLP(feat)[...,0].
// hidden features collapse analytically to bit features of (n,m); layer-1 is
// rank-1 + separable -> per-row table rn[n][10] + per-col table cm[m][10],
// computed inline per k_nw block.
// GEMM: fp16 2-term W-split:  logit = fp16(x) * (wh + wl)  [absmax-proven
//   1.95e-3]. MFMA 16x16x32_f16.
// R8 (split-K reverted — it added 32 MB HBM round-trip, net +4 µs):
//   (a) tile 128x64 -> 64x64, grid 1024 = 4 blocks/CU, LDS 24 KB: more
//       co-resident blocks to hide barrier/vmcnt drains with ZERO extra HBM
//       traffic (extra B re-reads are L2-hits; full Bt=4MB ~ per-XCD L2);
//   (b) X-cast block swizzle: Ah rows produced on the XCD that gemms them;
//   (c) softmax block->row swizzle: reads `out` from the XCD that wrote it.
//
// 4 dispatches: k_pre (sums) -> k_nw (MLP + X cast) -> k_gemm8 -> k_softmax2.
//
// ws layout (bytes):
//   rs      @ 0        : f32[1024]          row sums of weight
//   cs_part @ 4096     : f32[64][1024]      per-block partial col sums
//   Bt      @ 266240   : f16[1024][2048]    new_weight^T hi|lo   (4 MB)
//   Ah      @ 4460544  : f16[4096][1024]    fp16(X)              (8 MB)

#define RS_OFF      0
#define CSPART_OFF  4096
#define BT_OFF      266240
#define AH_OFF      4460544

typedef __attribute__((ext_vector_type(8))) _Float16 f16x8;
typedef __attribute__((ext_vector_type(4))) float f32x4;

__device__ __forceinline__ unsigned short f2h(float x) {
    _Float16 h = (_Float16)x;            // RNE
    unsigned short u;
    __builtin_memcpy(&u, &h, 2);
    return u;
}
__device__ __forceinline__ float h2f(unsigned short u) {
    _Float16 h;
    __builtin_memcpy(&h, &u, 2);
    return (float)h;
}
__device__ __forceinline__ void gld16(const void* g, void* l) {
    __builtin_amdgcn_global_load_lds(
        (const __attribute__((address_space(1))) unsigned*)g,
        (__attribute__((address_space(3))) unsigned*)l, 16, 0, 0);
}

// ---------------------------------------------------------------------------
// K1: row sums (wave per 4 rows, shuffle) + 64 partial colsum vectors.
__global__ __launch_bounds__(256) void k_pre(const float* __restrict__ w,
        float* __restrict__ rs, float* __restrict__ cs_part) {
    __shared__ float part[4][1024];
    int t = threadIdx.x;
    int lane = t & 63, wv = t >> 6;
    int r0 = blockIdx.x * 16 + wv * 4;
    float ccol[16];
    #pragma unroll
    for (int j = 0; j < 16; ++j) ccol[j] = 0.f;
    #pragma unroll
    for (int rr = 0; rr < 4; ++rr) {
        int row = r0 + rr;
        float rsum = 0.f;
        #pragma unroll
        for (int j = 0; j < 16; ++j) {
            float v = w[(size_t)row * 1024 + j * 64 + lane];
            ccol[j] += v;
            rsum += v;
        }
        #pragma unroll
        for (int o = 32; o; o >>= 1) rsum += __shfl_down(rsum, o);
        if (lane == 0) rs[row] = rsum;
    }
    #pragma unroll
    for (int j = 0; j < 16; ++j) part[wv][j * 64 + lane] = ccol[j];
    __syncthreads();
    #pragma unroll
    for (int j = 0; j < 4; ++j) {
        int c = t + j * 256;
        cs_part[(size_t)blockIdx.x * 1024 + c] =
            part[0][c] + part[1][c] + part[2][c] + part[3][c];
    }
}

// ---------------------------------------------------------------------------
// K2: blocks 0..1023: new_weight MLP on 32x32 tiles (inline rn/cm tables +
// colsum reduction), writing TRANSPOSED fp16 hi/lo Bt. Blocks 1024..2047:
// cast X -> fp16 Ah; row-swizzled so each XCD produces the Ah rows its gemm
// blocks will read (dispatch round-robins blocks over 8 XCDs).
__global__ __launch_bounds__(256) void k_nw(const float* __restrict__ w,
        const float* __restrict__ X,
        const float* __restrict__ rs, const float* __restrict__ cs_part,
        const float* __restrict__ W1, const float* __restrict__ b1,
        const float* __restrict__ W2, const float* __restrict__ b2,
        const float* __restrict__ W3, const float* __restrict__ b3,
        unsigned short* __restrict__ Bt, unsigned short* __restrict__ Ah) {
    __shared__ float sW1[630], sW2[100], sb1[10], sb2[10], sw3[10], sa[10];
    __shared__ float rs_loc[32], cs_loc[32];
    __shared__ float rn_loc[320], cm_loc[320];
    __shared__ float st[32][33];   // +1 pad: conflict-free column reads
    int t = threadIdx.x;
    if (blockIdx.x >= 1024) {
        int local = blockIdx.x - 1024;      // 0..1023
        // XCD of this block = (1024+local)%8 = local&7. Give it X rows in
        // [ (local&7)*512, +512 ): b2x covers rows 4*b2x..4*b2x+3.
        int b2x = (local & 7) * 128 + (local >> 3);
        #pragma unroll
        for (int p = 0; p < 4; ++p) {
            size_t idx = (size_t)b2x * 4096 + p * 1024 + t * 4;
            float4 v = *(const float4*)&X[idx];
            ushort4 h;
            h.x = f2h(v.x); h.y = f2h(v.y); h.z = f2h(v.z); h.w = f2h(v.w);
            *(ushort4*)&Ah[idx] = h;
        }
        return;
    }
    int n0 = (blockIdx.x & 31) * 32;   // weight-row base (k of gemm)
    int m0 = (blockIdx.x >> 5) * 32;   // weight-col base (n of gemm)
    const float inv = 1.0f / 1023.0f;

    for (int i = t; i < 630; i += 256) sW1[i] = W1[i];
    if (t < 100) sW2[t] = W2[t];
    if (t >= 128 && t < 138) { sb1[t - 128] = b1[t - 128]; sb2[t - 128] = b2[t - 128]; }
    if (t >= 160 && t < 170) sw3[t - 160] = W3[(t - 160) * 21];  // W3[:,0]
    if (t >= 192 && t < 224) rs_loc[t - 192] = rs[n0 + t - 192];
    if (t >= 224 && t < 256) {
        float s = 0.f;
        #pragma unroll
        for (int p = 0; p < 64; ++p) s += cs_part[(size_t)p * 1024 + m0 + (t - 224)];
        cs_loc[t - 224] = s;
    }
    float b30 = b3[0];
    __syncthreads();
    if (t < 10) sa[t] = sW1[t] - (sW1[10 + t] + sW1[20 + t]) * inv;
    // rn/cm tables for this block's 32 rows / 32 cols (640 values)
    for (int id = t; id < 640; id += 256) {
        int h = id % 10, i = (id / 10) & 31, side = id >= 320;
        if (!side) {
            int n = n0 + i;
            float v = rs_loc[i] * sW1[20 + h] * inv;
            #pragma unroll
            for (int j = 0; j < 10; j++) {
                float bit = (float)((n >> (9 - j)) & 1);
                v += bit * (sW1[(3 + j) * 10 + h] + sW1[(43 + j) * 10 + h]
                            - sW1[(23 + j) * 10 + h] * inv);
                v += (512.0f * inv) * sW1[(23 + j) * 10 + h];
            }
            rn_loc[i * 10 + h] = v;
        } else {
            int m = m0 + i;
            float v = cs_loc[i] * sW1[10 + h] * inv + sb1[h];
            #pragma unroll
            for (int j = 0; j < 10; j++) {
                float bit = (float)((m >> (9 - j)) & 1);
                v += bit * (sW1[(13 + j) * 10 + h] + sW1[(33 + j) * 10 + h]
                            - sW1[(53 + j) * 10 + h] * inv);
                v += (512.0f * inv) * sW1[(53 + j) * 10 + h];
            }
            cm_loc[i * 10 + h] = v;
        }
    }
    __syncthreads();
    int ml = t & 31;
    #pragma unroll
    for (int i = 0; i < 4; i++) {
        int nl = (t >> 5) + 8 * i;
        float wv = w[(size_t)(n0 + nl) * 1024 + m0 + ml];
        float h1[10];
        #pragma unroll
        for (int h = 0; h < 10; h++)
            h1[h] = fmaxf(wv * sa[h] + rn_loc[nl * 10 + h] + cm_loc[ml * 10 + h], 0.f);
        float u = b30;
        #pragma unroll
        for (int k = 0; k < 10; k++) {
            float h2 = sb2[k];
            #pragma unroll
            for (int h = 0; h < 10; h++) h2 += h1[h] * sW2[h * 10 + k];
            u += fmaxf(h2, 0.f) * sw3[k];
        }
        st[nl][ml] = wv + u;
    }
    __syncthreads();
    int mrow = t >> 3, kc = t & 7;
    unsigned short hi4[4], lo4[4];
    #pragma unroll
    for (int j = 0; j < 4; j++) {
        float v = st[kc * 4 + j][mrow];
        unsigned short h = f2h(v);
        hi4[j] = h;
        lo4[j] = f2h(v - h2f(h));
    }
    size_t base = (size_t)(m0 + mrow) * 2048 + n0 + kc * 4;
    *(ushort4*)&Bt[base]        = make_ushort4(hi4[0], hi4[1], hi4[2], hi4[3]);
    *(ushort4*)&Bt[base + 1024] = make_ushort4(lo4[0], lo4[1], lo4[2], lo4[3]);
}

// ---------------------------------------------------------------------------
// K3: C = relu(X @ Wn) via 2-phase fp16 MFMA (W split hi/lo, X single fp16).
// Tile 64(M)x64(N), BK=64, 4 waves, wave tile 32x32 (acc 2x2), LDS 24 KB.
// Grid 1024 = 4 blocks/CU: co-resident blocks hide each other's barrier and
// vmcnt drains [m114]; all extra B re-reads are L2-hits (no new HBM bytes —
// the R7 split-K mistake). XCD swizzle: xcd owns m in [xcd*512,(xcd+1)*512).
// Same per-output K accumulation order as R6 -> bit-identical numerics.
// XOR-swizzled LDS chunks (pos = row*8 + (seg ^ (row&7))): staging stays
// lane-contiguous for global_load_lds, frag reads spread over all bank-quads.
__global__ __launch_bounds__(256, 4) void k_gemm8(const unsigned short* __restrict__ Ah,
        const unsigned short* __restrict__ Bt, float* __restrict__ out) {
    __shared__ unsigned short sAh[64 * 64];                   // 8 KB
    __shared__ unsigned short sBh[64 * 64], sBl[64 * 64];     // 8 KB each
    int tid = threadIdx.x;
    int lane = tid & 63, w = tid >> 6;
    // b = (xcd, s): ty = xcd*8 + s/16 (64 m-tiles), tx = s%16 (16 n-tiles)
    int b = blockIdx.x;
    int xcd = b & 7, s = b >> 3;          // s in [0,128)
    int ty = (xcd << 3) | (s >> 4);
    int tx = s & 15;
    int n0 = tx * 64, m0 = ty * 64;
    int wm = (w >> 1) * 32, wn = (w & 1) * 32;
    int quad = lane >> 4, l16 = lane & 15;

    f32x4 acc[2][2];
    #pragma unroll
    for (int i = 0; i < 2; i++)
        #pragma unroll
        for (int j = 0; j < 2; j++) acc[i][j] = (f32x4)0.f;

    for (int it = 0; it < 16; ++it) {
        int kb = it * 64;
        __syncthreads();
        // A: 512 chunks (64 rows x 8 segs), 2 per thread
        #pragma unroll
        for (int s3 = 0; s3 < 2; ++s3) {
            int P = s3 * 256 + tid;
            int row = P >> 3;
            int seg = (P & 7) ^ (row & 7);
            int ldsOff = (s3 * 256 + w * 64) * 8;       // wave-uniform dst
            size_t ga = (size_t)(m0 + row) * 1024 + kb + seg * 8;
            gld16(&Ah[ga], &sAh[ldsOff]);
            // B: 512 chunks per buffer (64 rows x 8 segs), hi+lo
            size_t gb = (size_t)(n0 + row) * 2048 + kb + seg * 8;
            gld16(&Bt[gb], &sBh[ldsOff]);
            gld16(&Bt[gb + 1024], &sBl[ldsOff]);
        }
        __syncthreads();
        #pragma unroll
        for (int ks = 0; ks < 2; ++ks) {
            int segk = ks * 4 + quad;
            f16x8 ah[2], bh[2], bl[2];
            #pragma unroll
            for (int i = 0; i < 2; ++i) {
                int ra = wm + i * 16 + l16;
                int ca = (ra * 8 + (segk ^ (ra & 7))) * 8;
                ah[i] = *(const f16x8*)&sAh[ca];
            }
            #pragma unroll
            for (int j = 0; j < 2; ++j) {
                int rb = wn + j * 16 + l16;
                int cb = (rb * 8 + (segk ^ (rb & 7))) * 8;
                bh[j] = *(const f16x8*)&sBh[cb];
                bl[j] = *(const f16x8*)&sBl[cb];
            }
            #pragma unroll
            for (int i = 0; i < 2; ++i)
                #pragma unroll
                for (int j = 0; j < 2; ++j) {
                    acc[i][j] = __builtin_amdgcn_mfma_f32_16x16x32_f16(ah[i], bh[j], acc[i][j], 0, 0, 0);
                    acc[i][j] = __builtin_amdgcn_mfma_f32_16x16x32_f16(ah[i], bl[j], acc[i][j], 0, 0, 0);
                }
        }
    }
    // C/D layout: col = lane&15, row = quad*4 + reg  [measured m89/m91]
    #pragma unroll
    for (int i = 0; i < 2; ++i) {
        int mr = m0 + wm + i * 16 + quad * 4;
        #pragma unroll
        for (int j = 0; j < 2; ++j) {
            int nc = n0 + wn + j * 16 + l16;
            #pragma unroll
            for (int r = 0; r < 4; ++r)
                out[(size_t)(mr + r) * 1024 + nc] = fmaxf(acc[i][j][r], 0.f);
        }
    }
}

// ---------------------------------------------------------------------------
// K4: in-place row softmax, shuffle-based. Block->row swizzle: block b gets
// row (b&7)*512 + (b>>3), matching the XCD that wrote that row in k_gemm8
// -> reads are L2 write-back hits instead of HBM.
__global__ __launch_bounds__(256) void k_softmax2(float* __restrict__ C) {
    int b = blockIdx.x;
    int row = ((b & 7) << 9) + (b >> 3);
    int t = threadIdx.x, lane = t & 63, wv = t >> 6;
    __shared__ float red[8];
    float4 v = *(float4*)&C[(size_t)row * 1024 + t * 4];
    float lm = fmaxf(fmaxf(v.x, v.y), fmaxf(v.z, v.w));
    #pragma unroll
    for (int o = 32; o; o >>= 1) lm = fmaxf(lm, __shfl_down(lm, o));
    if (lane == 0) red[wv] = lm;
    __syncthreads();
    float mx = fmaxf(fmaxf(red[0], red[1]), fmaxf(red[2], red[3]));
    float4 e;
    e.x = __expf(v.x - mx); e.y = __expf(v.y - mx);
    e.z = __expf(v.z - mx); e.w = __expf(v.w - mx);
    float ls = e.x + e.y + e.z + e.w;
    #pragma unroll
    for (int o = 32; o; o >>= 1) ls += __shfl_down(ls, o);
    if (lane == 0) red[4 + wv] = ls;
    __syncthreads();
    float inv = 1.0f / (red[4] + red[5] + red[6] + red[7]);
    e.x *= inv; e.y *= inv; e.z *= inv; e.w *= inv;
    *(float4*)&C[(size_t)row * 1024 + t * 4] = e;
}

// ---------------------------------------------------------------------------
extern "C" void kernel_launch(void* const* d_in, const int* in_sizes, int n_in,
                              void* d_out, int out_size, void* d_ws, size_t ws_size,
                              hipStream_t stream) {
    const float* X  = (const float*)d_in[0];
    const float* W  = (const float*)d_in[1];
    // d_in[2] = hidden: analytic, never read
    const float* W1 = (const float*)d_in[3];
    const float* b1 = (const float*)d_in[4];
    const float* W2 = (const float*)d_in[5];
    const float* b2 = (const float*)d_in[6];
    const float* W3 = (const float*)d_in[7];
    const float* b3 = (const float*)d_in[8];

    char* wsb = (char*)d_ws;
    float* rs            = (float*)(wsb + RS_OFF);
    float* cs_part       = (float*)(wsb + CSPART_OFF);
    unsigned short* Bt   = (unsigned short*)(wsb + BT_OFF);
    unsigned short* Ah   = (unsigned short*)(wsb + AH_OFF);
    float* out = (float*)d_out;

    k_pre<<<64, 256, 0, stream>>>(W, rs, cs_part);
    k_nw<<<2048, 256, 0, stream>>>(W, X, rs, cs_part, W1, b1, W2, b2, W3, b3, Bt, Ah);
    k_gemm8<<<1024, 256, 0, stream>>>(Ah, Bt, out);
    k_softmax2<<<4096, 256, 0, stream>>>(out);
}

// Round 9
// 176.458 us; speedup vs baseline: 1.0425x; 1.0289x over previous
//
#include <hip/hip_runtime.h>
#include <hip/hip_bf16.h>
#include <stdint.h>

// out = softmax(relu(X @ new_weight)), new_weight = weight + MLP(feat)[...,0].
// hidden features collapse analytically to bit features of (n,m); layer-1 is
// rank-1 + separable -> per-row table rn[n][10] + per-col table cm[m][10],
// computed inline per k_nw block.
// GEMM (R9): single-phase fp16:  logit = fp16(x) * fp16(w).
//   Error budget: X and W each truncated at 2^-11 rel; measured 2-term absmax
//   was 1.95e-3 (X-only truncation) -> predicted ~3-5e-3 here, threshold
//   1.2e-2. Halves MFMA work, B LDS traffic, and Bt footprint vs R6.
// Config otherwise identical to R6 (best known, 179.8 us): tile 128x64,
// BK=64, grid 512, XCD swizzle, cast-in-nw, in-place softmax.
//
// 4 dispatches: k_pre (sums) -> k_nw (MLP + X cast) -> k_gemm9 -> k_softmax2.
//
// ws layout (bytes):
//   rs      @ 0        : f32[1024]          row sums of weight
//   cs_part @ 4096     : f32[64][1024]      per-block partial col sums
//   Bt      @ 266240   : f16[1024][1024]    new_weight^T         (2 MB)
//   Ah      @ 2363392  : f16[4096][1024]    fp16(X)              (8 MB)

#define RS_OFF      0
#define CSPART_OFF  4096
#define BT_OFF      266240
#define AH_OFF      2363392

typedef __attribute__((ext_vector_type(8))) _Float16 f16x8;
typedef __attribute__((ext_vector_type(4))) float f32x4;

__device__ __forceinline__ unsigned short f2h(float x) {
    _Float16 h = (_Float16)x;            // RNE
    unsigned short u;
    __builtin_memcpy(&u, &h, 2);
    return u;
}
__device__ __forceinline__ void gld16(const void* g, void* l) {
    __builtin_amdgcn_global_load_lds(
        (const __attribute__((address_space(1))) unsigned*)g,
        (__attribute__((address_space(3))) unsigned*)l, 16, 0, 0);
}

// ---------------------------------------------------------------------------
// K1: row sums (wave per 4 rows, shuffle) + 64 partial colsum vectors.
__global__ __launch_bounds__(256) void k_pre(const float* __restrict__ w,
        float* __restrict__ rs, float* __restrict__ cs_part) {
    __shared__ float part[4][1024];
    int t = threadIdx.x;
    int lane = t & 63, wv = t >> 6;
    int r0 = blockIdx.x * 16 + wv * 4;
    float ccol[16];
    #pragma unroll
    for (int j = 0; j < 16; ++j) ccol[j] = 0.f;
    #pragma unroll
    for (int rr = 0; rr < 4; ++rr) {
        int row = r0 + rr;
        float rsum = 0.f;
        #pragma unroll
        for (int j = 0; j < 16; ++j) {
            float v = w[(size_t)row * 1024 + j * 64 + lane];
            ccol[j] += v;
            rsum += v;
        }
        #pragma unroll
        for (int o = 32; o; o >>= 1) rsum += __shfl_down(rsum, o);
        if (lane == 0) rs[row] = rsum;
    }
    #pragma unroll
    for (int j = 0; j < 16; ++j) part[wv][j * 64 + lane] = ccol[j];
    __syncthreads();
    #pragma unroll
    for (int j = 0; j < 4; ++j) {
        int c = t + j * 256;
        cs_part[(size_t)blockIdx.x * 1024 + c] =
            part[0][c] + part[1][c] + part[2][c] + part[3][c];
    }
}

// ---------------------------------------------------------------------------
// K2: blocks 0..1023: new_weight MLP on 32x32 tiles (inline rn/cm tables +
// colsum reduction), writing TRANSPOSED fp16 Bt[m][n]. Blocks 1024..2047:
// cast X -> fp16 Ah (memory-bound; overlaps the compute-bound MLP blocks).
__global__ __launch_bounds__(256) void k_nw(const float* __restrict__ w,
        const float* __restrict__ X,
        const float* __restrict__ rs, const float* __restrict__ cs_part,
        const float* __restrict__ W1, const float* __restrict__ b1,
        const float* __restrict__ W2, const float* __restrict__ b2,
        const float* __restrict__ W3, const float* __restrict__ b3,
        unsigned short* __restrict__ Bt, unsigned short* __restrict__ Ah) {
    __shared__ float sW1[630], sW2[100], sb1[10], sb2[10], sw3[10], sa[10];
    __shared__ float rs_loc[32], cs_loc[32];
    __shared__ float rn_loc[320], cm_loc[320];
    __shared__ float st[32][33];   // +1 pad: conflict-free column reads
    int t = threadIdx.x;
    if (blockIdx.x >= 1024) {
        int b2x = blockIdx.x - 1024;        // 0..1023, 4096 floats each
        #pragma unroll
        for (int p = 0; p < 4; ++p) {
            size_t idx = (size_t)b2x * 4096 + p * 1024 + t * 4;
            float4 v = *(const float4*)&X[idx];
            ushort4 h;
            h.x = f2h(v.x); h.y = f2h(v.y); h.z = f2h(v.z); h.w = f2h(v.w);
            *(ushort4*)&Ah[idx] = h;
        }
        return;
    }
    int n0 = (blockIdx.x & 31) * 32;   // weight-row base (k of gemm)
    int m0 = (blockIdx.x >> 5) * 32;   // weight-col base (n of gemm)
    const float inv = 1.0f / 1023.0f;

    for (int i = t; i < 630; i += 256) sW1[i] = W1[i];
    if (t < 100) sW2[t] = W2[t];
    if (t >= 128 && t < 138) { sb1[t - 128] = b1[t - 128]; sb2[t - 128] = b2[t - 128]; }
    if (t >= 160 && t < 170) sw3[t - 160] = W3[(t - 160) * 21];  // W3[:,0]
    if (t >= 192 && t < 224) rs_loc[t - 192] = rs[n0 + t - 192];
    if (t >= 224 && t < 256) {
        float s = 0.f;
        #pragma unroll
        for (int p = 0; p < 64; ++p) s += cs_part[(size_t)p * 1024 + m0 + (t - 224)];
        cs_loc[t - 224] = s;
    }
    float b30 = b3[0];
    __syncthreads();
    if (t < 10) sa[t] = sW1[t] - (sW1[10 + t] + sW1[20 + t]) * inv;
    // rn/cm tables for this block's 32 rows / 32 cols (640 values)
    for (int id = t; id < 640; id += 256) {
        int h = id % 10, i = (id / 10) & 31, side = id >= 320;
        if (!side) {
            int n = n0 + i;
            float v = rs_loc[i] * sW1[20 + h] * inv;
            #pragma unroll
            for (int j = 0; j < 10; j++) {
                float bit = (float)((n >> (9 - j)) & 1);
                v += bit * (sW1[(3 + j) * 10 + h] + sW1[(43 + j) * 10 + h]
                            - sW1[(23 + j) * 10 + h] * inv);
                v += (512.0f * inv) * sW1[(23 + j) * 10 + h];
            }
            rn_loc[i * 10 + h] = v;
        } else {
            int m = m0 + i;
            float v = cs_loc[i] * sW1[10 + h] * inv + sb1[h];
            #pragma unroll
            for (int j = 0; j < 10; j++) {
                float bit = (float)((m >> (9 - j)) & 1);
                v += bit * (sW1[(13 + j) * 10 + h] + sW1[(33 + j) * 10 + h]
                            - sW1[(53 + j) * 10 + h] * inv);
                v += (512.0f * inv) * sW1[(53 + j) * 10 + h];
            }
            cm_loc[i * 10 + h] = v;
        }
    }
    __syncthreads();
    int ml = t & 31;
    #pragma unroll
    for (int i = 0; i < 4; i++) {
        int nl = (t >> 5) + 8 * i;
        float wv = w[(size_t)(n0 + nl) * 1024 + m0 + ml];
        float h1[10];
        #pragma unroll
        for (int h = 0; h < 10; h++)
            h1[h] = fmaxf(wv * sa[h] + rn_loc[nl * 10 + h] + cm_loc[ml * 10 + h], 0.f);
        float u = b30;
        #pragma unroll
        for (int k = 0; k < 10; k++) {
            float h2 = sb2[k];
            #pragma unroll
            for (int h = 0; h < 10; h++) h2 += h1[h] * sW2[h * 10 + k];
            u += fmaxf(h2, 0.f) * sw3[k];
        }
        st[nl][ml] = wv + u;
    }
    __syncthreads();
    int mrow = t >> 3, kc = t & 7;
    unsigned short hi4[4];
    #pragma unroll
    for (int j = 0; j < 4; j++)
        hi4[j] = f2h(st[kc * 4 + j][mrow]);
    size_t base = (size_t)(m0 + mrow) * 1024 + n0 + kc * 4;
    *(ushort4*)&Bt[base] = make_ushort4(hi4[0], hi4[1], hi4[2], hi4[3]);
}

// ---------------------------------------------------------------------------
// K3: C = relu(X @ Wn) via single-phase fp16 MFMA.
// Tile 128(M)x64(N), BK=64, 4 waves, wave tile 64x32 (acc 4x2), LDS 24 KB.
// XCD-aware swizzle: XCD k owns m-groups {4k..4k+3} x all 16 n-blocks ->
// per-XCD working set A 1 MB + B 2 MB stays L2-resident.
// XOR-swizzled LDS chunks (pos = row*8 + (seg ^ (row&7))): staging stays
// lane-contiguous for global_load_lds, frag reads spread over all bank-quads.
__global__ __launch_bounds__(256, 3) void k_gemm9(const unsigned short* __restrict__ Ah,
        const unsigned short* __restrict__ Bt, float* __restrict__ out) {
    __shared__ unsigned short sAh[128 * 64];                  // 16 KB
    __shared__ unsigned short sBh[64 * 64];                   //  8 KB
    int tid = threadIdx.x;
    int lane = tid & 63, w = tid >> 6;
    // tile swizzle: b = (xcd, slot); ty = xcd*4 + slot/16, tx = slot%16
    int b = blockIdx.x;
    int xcd = b & 7, s = b >> 3;
    int ty = (xcd << 2) | (s >> 4);
    int tx = s & 15;
    int n0 = tx * 64, m0 = ty * 128;
    int wm = (w >> 1) * 64, wn = (w & 1) * 32;
    int quad = lane >> 4, l16 = lane & 15;

    f32x4 acc[4][2];
    #pragma unroll
    for (int i = 0; i < 4; i++)
        #pragma unroll
        for (int j = 0; j < 2; j++) acc[i][j] = (f32x4)0.f;

    for (int it = 0; it < 16; ++it) {
        int kb = it * 64;
        __syncthreads();
        // A: 1024 chunks (128 rows x 8 segs), 4 per thread
        #pragma unroll
        for (int s2 = 0; s2 < 4; ++s2) {
            int P = s2 * 256 + tid;
            int row = P >> 3;
            int seg = (P & 7) ^ (row & 7);
            int ldsOff = (s2 * 256 + w * 64) * 8;       // wave-uniform dst
            size_t ga = (size_t)(m0 + row) * 1024 + kb + seg * 8;
            gld16(&Ah[ga], &sAh[ldsOff]);
        }
        // B: 512 chunks (64 rows x 8 segs), 2 per thread
        #pragma unroll
        for (int s2 = 0; s2 < 2; ++s2) {
            int P = s2 * 256 + tid;
            int row = P >> 3;
            int seg = (P & 7) ^ (row & 7);
            int ldsOff = (s2 * 256 + w * 64) * 8;
            size_t gb = (size_t)(n0 + row) * 1024 + kb + seg * 8;
            gld16(&Bt[gb], &sBh[ldsOff]);
        }
        __syncthreads();
        #pragma unroll
        for (int ks = 0; ks < 2; ++ks) {
            int segk = ks * 4 + quad;
            f16x8 ah[4], bh[2];
            #pragma unroll
            for (int i = 0; i < 4; ++i) {
                int ra = wm + i * 16 + l16;
                int ca = (ra * 8 + (segk ^ (ra & 7))) * 8;
                ah[i] = *(const f16x8*)&sAh[ca];
            }
            #pragma unroll
            for (int j = 0; j < 2; ++j) {
                int rb = wn + j * 16 + l16;
                int cb = (rb * 8 + (segk ^ (rb & 7))) * 8;
                bh[j] = *(const f16x8*)&sBh[cb];
            }
            #pragma unroll
            for (int i = 0; i < 4; ++i)
                #pragma unroll
                for (int j = 0; j < 2; ++j)
                    acc[i][j] = __builtin_amdgcn_mfma_f32_16x16x32_f16(ah[i], bh[j], acc[i][j], 0, 0, 0);
        }
    }
    // C/D layout: col = lane&15, row = quad*4 + reg  [measured m89/m91]
    #pragma unroll
    for (int i = 0; i < 4; ++i) {
        int mr = m0 + wm + i * 16 + quad * 4;
        #pragma unroll
        for (int j = 0; j < 2; ++j) {
            int nc = n0 + wn + j * 16 + l16;
            #pragma unroll
            for (int r = 0; r < 4; ++r)
                out[(size_t)(mr + r) * 1024 + nc] = fmaxf(acc[i][j][r], 0.f);
        }
    }
}

// ---------------------------------------------------------------------------
// K4: in-place row softmax, shuffle-based (2 barriers). [R6 version]
__global__ __launch_bounds__(256) void k_softmax2(float* __restrict__ C) {
    int row = blockIdx.x, t = threadIdx.x, lane = t & 63, wv = t >> 6;
    __shared__ float red[8];
    float4 v = *(float4*)&C[(size_t)row * 1024 + t * 4];
    float lm = fmaxf(fmaxf(v.x, v.y), fmaxf(v.z, v.w));
    #pragma unroll
    for (int o = 32; o; o >>= 1) lm = fmaxf(lm, __shfl_down(lm, o));
    if (lane == 0) red[wv] = lm;
    __syncthreads();
    float mx = fmaxf(fmaxf(red[0], red[1]), fmaxf(red[2], red[3]));
    float4 e;
    e.x = __expf(v.x - mx); e.y = __expf(v.y - mx);
    e.z = __expf(v.z - mx); e.w = __expf(v.w - mx);
    float ls = e.x + e.y + e.z + e.w;
    #pragma unroll
    for (int o = 32; o; o >>= 1) ls += __shfl_down(ls, o);
    if (lane == 0) red[4 + wv] = ls;
    __syncthreads();
    float inv = 1.0f / (red[4] + red[5] + red[6] + red[7]);
    e.x *= inv; e.y *= inv; e.z *= inv; e.w *= inv;
    *(float4*)&C[(size_t)row * 1024 + t * 4] = e;
}

// ---------------------------------------------------------------------------
extern "C" void kernel_launch(void* const* d_in, const int* in_sizes, int n_in,
                              void* d_out, int out_size, void* d_ws, size_t ws_size,
                              hipStream_t stream) {
    const float* X  = (const float*)d_in[0];
    const float* W  = (const float*)d_in[1];
    // d_in[2] = hidden: analytic, never read
    const float* W1 = (const float*)d_in[3];
    const float* b1 = (const float*)d_in[4];
    const float* W2 = (const float*)d_in[5];
    const float* b2 = (const float*)d_in[6];
    const float* W3 = (const float*)d_in[7];
    const float* b3 = (const float*)d_in[8];

    char* wsb = (char*)d_ws;
    float* rs            = (float*)(wsb + RS_OFF);
    float* cs_part       = (float*)(wsb + CSPART_OFF);
    unsigned short* Bt   = (unsigned short*)(wsb + BT_OFF);
    unsigned short* Ah   = (unsigned short*)(wsb + AH_OFF);
    float* out = (float*)d_out;

    k_pre<<<64, 256, 0, stream>>>(W, rs, cs_part);
    k_nw<<<2048, 256, 0, stream>>>(W, X, rs, cs_part, W1, b1, W2, b2, W3, b3, Bt, Ah);
    k_gemm9<<<512, 256, 0, stream>>>(Ah, Bt, out);
    k_softmax2<<<4096, 256, 0, stream>>>(out);
}